// Round 6
// baseline (287.140 us; speedup 1.0000x reference)
//
#include <hip/hip_runtime.h>

typedef short bf16x8 __attribute__((ext_vector_type(8)));
typedef float f32x4 __attribute__((ext_vector_type(4)));
typedef unsigned long long u64;

#define N_NODES 4096
#define N_EDGES 16384
#define FN 128
#define FE 64
#define NJS 8
#define EJS 16
#define WPR 64   // packed u64 words per row (4096 bits)

#define PACK_BLOCKS ((N_NODES + N_EDGES) / 4)   // 5120
#define NPROJ_BLOCKS (N_NODES / 4)              // 1024
#define EPROJ_BLOCKS (N_EDGES / 4)              // 4096
#define PREPN_BLOCKS (N_NODES / 64)             // 64
#define PREPE_BLOCKS (N_EDGES / 64)             // 256
#define FRONT_BLOCKS (PACK_BLOCKS + NPROJ_BLOCKS + EPROJ_BLOCKS + PREPN_BLOCKS + PREPE_BLOCKS)

__device__ __forceinline__ float lrelu(float x) { return x >= 0.f ? x : 0.01f * x; }
// float -> bf16 round-to-nearest-even (finite inputs only)
__device__ __forceinline__ unsigned short f2bf(float f) {
    unsigned int x = __float_as_uint(f);
    return (unsigned short)((x + 0x7fffu + ((x >> 16) & 1u)) >> 16);
}

// ---- prep: src[j][f] f32 -> dst[j/8][F][8] bf16 (MFMA A-frag friendly) ----
__device__ __forceinline__ void prep_b(
    const float* __restrict__ src, unsigned short* __restrict__ dst,
    int j0, int F, int lf, float* tile /* [64][F+1] */) {
    const int t = threadIdx.x;
    const int P = F + 1;
    for (int it = 0; it < (F >> 4); ++it) {
        int idx = (it * 256 + t) * 4;
        int j = idx >> lf, f = idx & (F - 1);
        float4 v = *(const float4*)(src + (size_t)(j0 + j) * F + f);
        tile[j * P + f + 0] = v.x; tile[j * P + f + 1] = v.y;
        tile[j * P + f + 2] = v.z; tile[j * P + f + 3] = v.w;
    }
    __syncthreads();
    for (int it = 0; it < (F >> 5); ++it) {
        int c = it * 256 + t;
        int jo = c >> lf, f = c & (F - 1);
        bf16x8 v;
#pragma unroll
        for (int e = 0; e < 8; ++e) v[e] = (short)f2bf(tile[(jo * 8 + e) * P + f]);
        *(bf16x8*)(dst + (((size_t)(j0 >> 3) + jo) * F + f) * 8) = v;
    }
}

// ---- kernel 1 (fused front): pack masks + node/edge proj + prep ----
__global__ __launch_bounds__(256) void k_front(
    const float* __restrict__ nf, const float* __restrict__ ef,
    const int* __restrict__ adj, const int* __restrict__ eadj,
    const float* __restrict__ Wn, const float* __restrict__ We,
    const float* __restrict__ pvn, const float* __restrict__ pve,
    u64* __restrict__ adjP, u64* __restrict__ eadjP,
    float* __restrict__ alpha, float* __restrict__ beta, float* __restrict__ gamma,
    float* __restrict__ betaE,
    unsigned short* __restrict__ XbN, unsigned short* __restrict__ XbE) {
    __shared__ float smem[8256];   // 33 KB, union across branches
    int bx = blockIdx.x;
    const int wv = threadIdx.x >> 6, ln = threadIdx.x & 63;

    if (bx < PACK_BLOCKS) {
        // pack: word = (i>>8)*4 + (i&3), bit = (i>>2)&63
        const int row = bx * 4 + wv;
        const int* src;
        u64* dst;
        if (row < N_EDGES) {
            src = eadj + (size_t)row * N_NODES;
            dst = eadjP + (size_t)row * WPR;
        } else {
            src = adj + (size_t)(row - N_EDGES) * N_NODES;
            dst = adjP + (size_t)(row - N_EDGES) * WPR;
        }
        int4 v[16];
#pragma unroll
        for (int c = 0; c < 16; ++c) v[c] = *(const int4*)(src + c * 256 + ln * 4);
#pragma unroll
        for (int c = 0; c < 16; ++c) {
            u64 b0 = __ballot(v[c].x > 0);
            u64 b1 = __ballot(v[c].y > 0);
            u64 b2 = __ballot(v[c].z > 0);
            u64 b3 = __ballot(v[c].w > 0);
            if (ln < 4) dst[c * 4 + ln] = (ln == 0) ? b0 : (ln == 1) ? b1 : (ln == 2) ? b2 : b3;
        }
        return;
    }
    bx -= PACK_BLOCKS;
    if (bx < NPROJ_BLOCKS) {
        float* row = smem;   // [4][FN]
        const int i = bx * 4 + wv;
        float2 r2 = *(const float2*)(nf + (size_t)i * FN + ln * 2);
        row[wv * FN + ln * 2] = r2.x; row[wv * FN + ln * 2 + 1] = r2.y;
        __syncthreads();
        float h0 = 0.f, h1 = 0.f;
#pragma unroll 8
        for (int k = 0; k < FN; ++k) {
            float nv = row[wv * FN + k];
            float2 w2 = *(const float2*)(Wn + (size_t)k * FN + ln * 2);
            h0 = fmaf(nv, w2.x, h0); h1 = fmaf(nv, w2.y, h1);
        }
        float2 as = *(const float2*)(pvn + ln * 2);
        float2 an = *(const float2*)(pvn + FN + ln * 2);
        float2 bs = *(const float2*)(pve + ln * 2);
        float pa = h0 * as.x + h1 * as.y;
        float pb = h0 * an.x + h1 * an.y;
        float pg = h0 * bs.x + h1 * bs.y;
#pragma unroll
        for (int off = 32; off > 0; off >>= 1) {
            pa += __shfl_down(pa, off, 64);
            pb += __shfl_down(pb, off, 64);
            pg += __shfl_down(pg, off, 64);
        }
        if (ln == 0) { alpha[i] = pa; beta[i] = pb; gamma[i] = pg; }
        return;
    }
    bx -= NPROJ_BLOCKS;
    if (bx < EPROJ_BLOCKS) {
        float* row = smem;   // [4][FE]
        const int e = bx * 4 + wv;
        row[wv * FE + ln] = ef[(size_t)e * FE + ln];
        __syncthreads();
        float h = 0.f;
#pragma unroll 8
        for (int k = 0; k < FE; ++k)
            h = fmaf(row[wv * FE + k], We[(size_t)k * FE + ln], h);
        float p = h * pve[FN + ln];
#pragma unroll
        for (int off = 32; off > 0; off >>= 1) p += __shfl_down(p, off, 64);
        if (ln == 0) betaE[e] = p;
        return;
    }
    bx -= EPROJ_BLOCKS;
    if (bx < PREPN_BLOCKS) {
        prep_b(nf, XbN, bx * 64, FN, 7, smem);
        return;
    }
    bx -= PREPN_BLOCKS;
    prep_b(ef, XbE, bx * 64, FE, 6, smem);
}

// ---- kernel 2: global maxes, 1024 threads/block ----
__global__ __launch_bounds__(1024) void k_maxes(
    const float* __restrict__ beta, const float* __restrict__ betaE,
    float* __restrict__ maxes) {
    const float* src = blockIdx.x == 0 ? beta : betaE;
    const int n = blockIdx.x == 0 ? N_NODES : N_EDGES;
    float m = -3.0e38f;
#pragma unroll
    for (int t = threadIdx.x * 4; t < n; t += 4096) {
        float4 v = *(const float4*)(src + t);
        m = fmaxf(m, fmaxf(fmaxf(v.x, v.y), fmaxf(v.z, v.w)));
    }
#pragma unroll
    for (int off = 32; off > 0; off >>= 1) m = fmaxf(m, __shfl_down(m, off, 64));
    __shared__ float sm[16];
    if ((threadIdx.x & 63) == 0) sm[threadIdx.x >> 6] = m;
    __syncthreads();
    if (threadIdx.x == 0) {
        float mm = sm[0];
#pragma unroll
        for (int w = 1; w < 16; ++w) mm = fmaxf(mm, sm[w]);
        maxes[blockIdx.x] = mm;
    }
}

// ---- kernel 3: node attention. Wave owns 32 i (2 frags); coalesced mask windows + bpermute ----
__global__ __launch_bounds__(256) void k_node_att(
    const unsigned short* __restrict__ Xb,   // [512][128][8] bf16
    const u64* __restrict__ adjP,
    const float* __restrict__ alpha, const float* __restrict__ beta,
    const float* __restrict__ maxes,
    float* __restrict__ accP, float* __restrict__ zP, float* __restrict__ degP) {
    const int t = threadIdx.x, l = t & 63, wid = t >> 6;
    const int l15 = l & 15, lq = l >> 4;
    const int bj = blockIdx.y;
    const int j0 = bj * (N_NODES / NJS);       // 512
    const int bx = blockIdx.x;
    const int i0 = bx * 128 + wid * 32;        // wave base (32 i)
    const float a0 = alpha[i0 + l15], a1 = alpha[i0 + 16 + l15];
    const float m0 = lrelu(a0 + maxes[0]), m1 = lrelu(a1 + maxes[0]);
    const int wordbase = (bx >> 1) * 4;        // (i>>8)*4, block-uniform
    const int bbb = (bx * 32) & 63;            // 0 or 32: block's 32-bit field
    const int mybit = wid * 8 + (l15 >> 2);    // +4 for iq=1
    f32x4 acc0[8] = {}, acc1[8] = {};
    float z0 = 0.f, d0 = 0.f, z1 = 0.f, d1 = 0.f;
    const u64* mrow = adjP + (size_t)j0 * WPR + wordbase + (l & 3);
    const int lr = l >> 2;                     // window row 0..15
    const unsigned short* xb0 = Xb + (((size_t)(j0 >> 3) + lq) * FN + l15) * 8;
    const float* bb0 = beta + j0 + lq * 8;

    for (int ks = 0; ks < 16; ++ks) {
        const int jb = ks * 32;
        u64 w64_0 = mrow[(size_t)(jb + lr) * WPR];
        u64 w64_1 = mrow[(size_t)(jb + 16 + lr) * WPR];
        unsigned mk0 = (unsigned)(w64_0 >> bbb);
        unsigned mk1 = (unsigned)(w64_1 >> bbb);
        float4 b0v = *(const float4*)(bb0 + jb);
        float4 b1v = *(const float4*)(bb0 + jb + 4);
        float bv[8] = {b0v.x, b0v.y, b0v.z, b0v.w, b1v.x, b1v.y, b1v.z, b1v.w};
        bf16x8 wf0, wf1;
#pragma unroll
        for (int e = 0; e < 8; ++e) {
            int jloc = lq * 8 + e;
            int srcl = (jloc & 15) * 4 + (l15 & 3);
            unsigned wlo = __shfl(mk0, srcl, 64);
            unsigned whi = __shfl(mk1, srcl, 64);
            unsigned wsel = (lq < 2) ? wlo : whi;
            int mka = (int)((wsel >> mybit) & 1u);
            int mkb = (int)((wsel >> (mybit + 4)) & 1u);
            float s0 = lrelu(a0 + bv[e]);
            float w0 = mka ? __expf(s0 - m0) : 0.f;
            float s1 = lrelu(a1 + bv[e]);
            float w1 = mkb ? __expf(s1 - m1) : 0.f;
            z0 += w0; d0 += (float)mka;
            z1 += w1; d1 += (float)mkb;
            wf0[e] = (short)f2bf(w0);
            wf1[e] = (short)f2bf(w1);
        }
        const unsigned short* xa = xb0 + (size_t)(jb >> 3) * (FN * 8);
#pragma unroll
        for (int mi = 0; mi < 8; ++mi) {
            bf16x8 a = *(const bf16x8*)(xa + mi * 128);
            acc0[mi] = __builtin_amdgcn_mfma_f32_16x16x32_bf16(a, wf0, acc0[mi], 0, 0, 0);
            acc1[mi] = __builtin_amdgcn_mfma_f32_16x16x32_bf16(a, wf1, acc1[mi], 0, 0, 0);
        }
    }
    z0 += __shfl_xor(z0, 16, 64); z0 += __shfl_xor(z0, 32, 64);
    d0 += __shfl_xor(d0, 16, 64); d0 += __shfl_xor(d0, 32, 64);
    z1 += __shfl_xor(z1, 16, 64); z1 += __shfl_xor(z1, 32, 64);
    d1 += __shfl_xor(d1, 16, 64); d1 += __shfl_xor(d1, 32, 64);
    if (l < 16) {
        zP[bj * N_NODES + i0 + l] = z0;  degP[bj * N_NODES + i0 + l] = d0;
        zP[bj * N_NODES + i0 + 16 + l] = z1;  degP[bj * N_NODES + i0 + 16 + l] = d1;
    }
#pragma unroll
    for (int mi = 0; mi < 8; ++mi) {
        *(f32x4*)(accP + ((size_t)bj * N_NODES + i0 + l15) * FN + mi * 16 + lq * 4) = acc0[mi];
        *(f32x4*)(accP + ((size_t)bj * N_NODES + i0 + 16 + l15) * FN + mi * 16 + lq * 4) = acc1[mi];
    }
}

// ---- kernel 4: edge attention, same structure (F=64) ----
__global__ __launch_bounds__(256) void k_edge_att(
    const unsigned short* __restrict__ Xb,   // [2048][64][8] bf16
    const u64* __restrict__ eadjP,
    const float* __restrict__ gamma, const float* __restrict__ betaE,
    const float* __restrict__ maxes,
    float* __restrict__ accP, float* __restrict__ zP, float* __restrict__ degP) {
    const int t = threadIdx.x, l = t & 63, wid = t >> 6;
    const int l15 = l & 15, lq = l >> 4;
    const int bj = blockIdx.y;
    const int j0 = bj * (N_EDGES / EJS);       // 1024
    const int bx = blockIdx.x;
    const int i0 = bx * 128 + wid * 32;
    const float a0 = gamma[i0 + l15], a1 = gamma[i0 + 16 + l15];
    const float m0 = lrelu(a0 + maxes[1]), m1 = lrelu(a1 + maxes[1]);
    const int wordbase = (bx >> 1) * 4;
    const int bbb = (bx * 32) & 63;
    const int mybit = wid * 8 + (l15 >> 2);
    f32x4 acc0[4] = {}, acc1[4] = {};
    float z0 = 0.f, d0 = 0.f, z1 = 0.f, d1 = 0.f;
    const u64* mrow = eadjP + (size_t)j0 * WPR + wordbase + (l & 3);
    const int lr = l >> 2;
    const unsigned short* xb0 = Xb + (((size_t)(j0 >> 3) + lq) * FE + l15) * 8;
    const float* bb0 = betaE + j0 + lq * 8;

    for (int ks = 0; ks < 32; ++ks) {
        const int jb = ks * 32;
        u64 w64_0 = mrow[(size_t)(jb + lr) * WPR];
        u64 w64_1 = mrow[(size_t)(jb + 16 + lr) * WPR];
        unsigned mk0 = (unsigned)(w64_0 >> bbb);
        unsigned mk1 = (unsigned)(w64_1 >> bbb);
        float4 b0v = *(const float4*)(bb0 + jb);
        float4 b1v = *(const float4*)(bb0 + jb + 4);
        float bv[8] = {b0v.x, b0v.y, b0v.z, b0v.w, b1v.x, b1v.y, b1v.z, b1v.w};
        bf16x8 wf0, wf1;
#pragma unroll
        for (int e = 0; e < 8; ++e) {
            int jloc = lq * 8 + e;
            int srcl = (jloc & 15) * 4 + (l15 & 3);
            unsigned wlo = __shfl(mk0, srcl, 64);
            unsigned whi = __shfl(mk1, srcl, 64);
            unsigned wsel = (lq < 2) ? wlo : whi;
            int mka = (int)((wsel >> mybit) & 1u);
            int mkb = (int)((wsel >> (mybit + 4)) & 1u);
            float s0 = lrelu(a0 + bv[e]);
            float w0 = mka ? __expf(s0 - m0) : 0.f;
            float s1 = lrelu(a1 + bv[e]);
            float w1 = mkb ? __expf(s1 - m1) : 0.f;
            z0 += w0; d0 += (float)mka;
            z1 += w1; d1 += (float)mkb;
            wf0[e] = (short)f2bf(w0);
            wf1[e] = (short)f2bf(w1);
        }
        const unsigned short* xa = xb0 + (size_t)(jb >> 3) * (FE * 8);
#pragma unroll
        for (int mi = 0; mi < 4; ++mi) {
            bf16x8 a = *(const bf16x8*)(xa + mi * 128);
            acc0[mi] = __builtin_amdgcn_mfma_f32_16x16x32_bf16(a, wf0, acc0[mi], 0, 0, 0);
            acc1[mi] = __builtin_amdgcn_mfma_f32_16x16x32_bf16(a, wf1, acc1[mi], 0, 0, 0);
        }
    }
    z0 += __shfl_xor(z0, 16, 64); z0 += __shfl_xor(z0, 32, 64);
    d0 += __shfl_xor(d0, 16, 64); d0 += __shfl_xor(d0, 32, 64);
    z1 += __shfl_xor(z1, 16, 64); z1 += __shfl_xor(z1, 32, 64);
    d1 += __shfl_xor(d1, 16, 64); d1 += __shfl_xor(d1, 32, 64);
    if (l < 16) {
        zP[bj * N_NODES + i0 + l] = z0;  degP[bj * N_NODES + i0 + l] = d0;
        zP[bj * N_NODES + i0 + 16 + l] = z1;  degP[bj * N_NODES + i0 + 16 + l] = d1;
    }
#pragma unroll
    for (int mi = 0; mi < 4; ++mi) {
        *(f32x4*)(accP + ((size_t)bj * N_NODES + i0 + l15) * FE + mi * 16 + lq * 4) = acc0[mi];
        *(f32x4*)(accP + ((size_t)bj * N_NODES + i0 + 16 + l15) * FE + mi * 16 + lq * 4) = acc1[mi];
    }
}

// ---- kernel 5: node epilogue ----
__global__ __launch_bounds__(256) void k_node_out(
    const float* __restrict__ accP, const float* __restrict__ zP,
    const float* __restrict__ degP, const float* __restrict__ Wn,
    float* __restrict__ out) {
    __shared__ float ml[4][FN];
    const int wv = threadIdx.x >> 6, ln = threadIdx.x & 63;
    const int i = blockIdx.x * 4 + wv;
    float s0 = 0.f, s1 = 0.f;
#pragma unroll
    for (int js = 0; js < NJS; ++js) {
        float2 v = *(const float2*)(accP + ((size_t)js * N_NODES + i) * FN + ln * 2);
        s0 += v.x; s1 += v.y;
    }
    float z = 0.f, d = 0.f;
#pragma unroll
    for (int js = 0; js < NJS; ++js) { z += zP[js * N_NODES + i]; d += degP[js * N_NODES + i]; }
    float zd = z * d;
    float inv = zd > 0.f ? 1.f / zd : 0.f;
    ml[wv][ln * 2] = s0 * inv; ml[wv][ln * 2 + 1] = s1 * inv;
    __syncthreads();
    float o0 = 0.f, o1 = 0.f;
#pragma unroll 8
    for (int k = 0; k < FN; ++k) {
        float mvv = ml[wv][k];
        float2 w2 = *(const float2*)(Wn + (size_t)k * FN + ln * 2);
        o0 = fmaf(mvv, w2.x, o0); o1 = fmaf(mvv, w2.y, o1);
    }
    out[(size_t)i * 192 + ln * 2] = lrelu(o0);
    out[(size_t)i * 192 + ln * 2 + 1] = lrelu(o1);
}

// ---- kernel 6: edge epilogue ----
__global__ __launch_bounds__(256) void k_edge_out(
    const float* __restrict__ accP, const float* __restrict__ zP,
    const float* __restrict__ degP, const float* __restrict__ We,
    float* __restrict__ out) {
    __shared__ float ml[4][FE];
    const int wv = threadIdx.x >> 6, ln = threadIdx.x & 63;
    const int i = blockIdx.x * 4 + wv;
    float s = 0.f;
#pragma unroll
    for (int js = 0; js < EJS; ++js)
        s += accP[((size_t)js * N_NODES + i) * FE + ln];
    float z = 0.f, d = 0.f;
#pragma unroll
    for (int js = 0; js < EJS; ++js) { z += zP[js * N_NODES + i]; d += degP[js * N_NODES + i]; }
    float zd = z * d;
    float inv = zd > 0.f ? 1.f / zd : 0.f;
    ml[wv][ln] = s * inv;
    __syncthreads();
    float o = 0.f;
#pragma unroll 8
    for (int k = 0; k < FE; ++k)
        o = fmaf(ml[wv][k], We[(size_t)k * FE + ln], o);
    out[(size_t)i * 192 + 128 + ln] = lrelu(o);
}

extern "C" void kernel_launch(void* const* d_in, const int* in_sizes, int n_in,
                              void* d_out, int out_size, void* d_ws, size_t ws_size,
                              hipStream_t stream) {
    (void)in_sizes; (void)n_in; (void)out_size; (void)ws_size;
    const float* nf   = (const float*)d_in[0];
    const float* ef   = (const float*)d_in[1];
    const int*   adj  = (const int*)d_in[2];
    const int*   eadj = (const int*)d_in[3];
    const float* Wn   = (const float*)d_in[4];
    const float* We   = (const float*)d_in[5];
    const float* pvn  = (const float*)d_in[6];
    const float* pve  = (const float*)d_in[7];
    float* out = (float*)d_out;

    u64* adjP  = (u64*)d_ws;                            // 2 MB
    u64* eadjP = adjP + (size_t)N_NODES * WPR;          // 8 MB
    float* alpha = (float*)(eadjP + (size_t)N_EDGES * WPR);
    float* beta  = alpha + 4096;
    float* gamma = beta + 4096;
    float* betaE = gamma + 4096;
    float* maxes = betaE + 16384;                       // 64 (padded)
    unsigned short* XbN = (unsigned short*)(maxes + 64);          // 1 MB
    unsigned short* XbE = XbN + (size_t)(N_NODES / 8) * FN * 8;   // 2 MB
    float* accN = (float*)(XbE + (size_t)(N_EDGES / 8) * FE * 8); // 16.8 MB
    float* zN   = accN + (size_t)NJS * N_NODES * FN;
    float* degN = zN + (size_t)NJS * N_NODES;
    float* accE = degN + (size_t)NJS * N_NODES;                   // 16.8 MB
    float* zE   = accE + (size_t)EJS * N_NODES * FE;
    float* degE = zE + (size_t)EJS * N_NODES;

    k_front<<<FRONT_BLOCKS, 256, 0, stream>>>(nf, ef, adj, eadj, Wn, We, pvn, pve,
                                              adjP, eadjP, alpha, beta, gamma, betaE, XbN, XbE);
    k_maxes<<<2, 1024, 0, stream>>>(beta, betaE, maxes);
    // ATTRIBUTION PROBE: att kernels launched twice (idempotent, deterministic).
    k_node_att<<<dim3(N_NODES / 128, NJS), 256, 0, stream>>>(XbN, adjP, alpha, beta, maxes, accN, zN, degN);
    k_node_att<<<dim3(N_NODES / 128, NJS), 256, 0, stream>>>(XbN, adjP, alpha, beta, maxes, accN, zN, degN);
    k_edge_att<<<dim3(N_NODES / 128, EJS), 256, 0, stream>>>(XbE, eadjP, gamma, betaE, maxes, accE, zE, degE);
    k_edge_att<<<dim3(N_NODES / 128, EJS), 256, 0, stream>>>(XbE, eadjP, gamma, betaE, maxes, accE, zE, degE);
    k_node_out<<<N_NODES / 4, 256, 0, stream>>>(accN, zN, degN, Wn, out);
    k_edge_out<<<N_NODES / 4, 256, 0, stream>>>(accE, zE, degE, We, out);
}

// Round 7
// 201.025 us; speedup vs baseline: 1.4284x; 1.4284x over previous
//
#include <hip/hip_runtime.h>

typedef short bf16x8 __attribute__((ext_vector_type(8)));
typedef float f32x4 __attribute__((ext_vector_type(4)));
typedef unsigned long long u64;

#define N_NODES 4096
#define N_EDGES 16384
#define FN 128
#define FE 64
#define NJS 16
#define EJS 32
#define TWN 64    // maskTN u64 words per row (4096 j-bits)
#define TWE 256   // maskTE u64 words per row (16384 j-bits)

#define PACKE_BLOCKS (256 * 64)   // edge tiles (jt 256 x it 64)
#define PACKN_BLOCKS (64 * 64)    // node tiles
#define PACK_BLOCKS (PACKE_BLOCKS + PACKN_BLOCKS)     // 20480
#define NPROJ_BLOCKS (N_NODES / 4)                    // 1024
#define EPROJ_BLOCKS (N_EDGES / 4)                    // 4096
#define PREPN_BLOCKS (N_NODES / 64)                   // 64
#define PREPE_BLOCKS (N_EDGES / 64)                   // 256
#define FRONT_BLOCKS (PACK_BLOCKS + NPROJ_BLOCKS + EPROJ_BLOCKS + PREPN_BLOCKS + PREPE_BLOCKS)

#define ATTN_BLOCKS (32 * NJS)    // 512
#define ATTE_BLOCKS (32 * EJS)    // 1024

__device__ __forceinline__ float lrelu(float x) { return x >= 0.f ? x : 0.01f * x; }
// float -> bf16 round-to-nearest-even (finite inputs only)
__device__ __forceinline__ unsigned short f2bf(float f) {
    unsigned int x = __float_as_uint(f);
    return (unsigned short)((x + 0x7fffu + ((x >> 16) & 1u)) >> 16);
}

// ---- prep: src[j][f] f32 -> dst[j/8][F][8] bf16 (MFMA A-frag friendly) ----
__device__ __forceinline__ void prep_b(
    const float* __restrict__ src, unsigned short* __restrict__ dst,
    int j0, int F, int lf, float* tile /* [64][F+1] */) {
    const int t = threadIdx.x;
    const int P = F + 1;
    for (int it = 0; it < (F >> 4); ++it) {
        int idx = (it * 256 + t) * 4;
        int j = idx >> lf, f = idx & (F - 1);
        float4 v = *(const float4*)(src + (size_t)(j0 + j) * F + f);
        tile[j * P + f + 0] = v.x; tile[j * P + f + 1] = v.y;
        tile[j * P + f + 2] = v.z; tile[j * P + f + 3] = v.w;
    }
    __syncthreads();
    for (int it = 0; it < (F >> 5); ++it) {
        int c = it * 256 + t;
        int jo = c >> lf, f = c & (F - 1);
        bf16x8 v;
#pragma unroll
        for (int e = 0; e < 8; ++e) v[e] = (short)f2bf(tile[(jo * 8 + e) * P + f]);
        *(bf16x8*)(dst + (((size_t)(j0 >> 3) + jo) * F + f) * 8) = v;
    }
}

// ---- kernel 1 (fused front): transposed bit-pack + projections + prep ----
__global__ __launch_bounds__(256) void k_front(
    const float* __restrict__ nf, const float* __restrict__ ef,
    const int* __restrict__ adj, const int* __restrict__ eadj,
    const float* __restrict__ Wn, const float* __restrict__ We,
    const float* __restrict__ pvn, const float* __restrict__ pve,
    u64* __restrict__ maskTN, u64* __restrict__ maskTE,
    float* __restrict__ alpha, float* __restrict__ beta, float* __restrict__ gamma,
    float* __restrict__ betaE,
    unsigned short* __restrict__ XbN, unsigned short* __restrict__ XbE) {
    __shared__ float smem[8256];   // 33 KB, union across branches
    int bx = blockIdx.x;
    const int t = threadIdx.x;
    const int wv = t >> 6, ln = t & 63;

    if (bx < PACK_BLOCKS) {
        // transposed pack: maskT[i][word jt] bit (j&63) = src[j][i] > 0
        const int* src; u64* dst; int jt, it, TW;
        if (bx < PACKE_BLOCKS) {
            jt = bx >> 6; it = bx & 63; src = eadj; dst = maskTE; TW = TWE;
        } else {
            int b2 = bx - PACKE_BLOCKS;
            jt = b2 >> 6; it = b2 & 63; src = adj; dst = maskTN; TW = TWN;
        }
        const int j0 = jt * 64, i0 = it * 64;
        int* smi = (int*)smem;   // [64][65]
#pragma unroll
        for (int p = 0; p < 4; ++p) {
            int idx = p * 256 + t;
            int row = idx >> 4, c4 = (idx & 15) * 4;
            int4 v = *(const int4*)(src + (size_t)(j0 + row) * N_NODES + i0 + c4);
            smi[row * 65 + c4 + 0] = v.x; smi[row * 65 + c4 + 1] = v.y;
            smi[row * 65 + c4 + 2] = v.z; smi[row * 65 + c4 + 3] = v.w;
        }
        __syncthreads();
        u64 myw = 0;
#pragma unroll
        for (int q = 0; q < 16; ++q) {
            int iloc = wv * 16 + q;
            int val = smi[ln * 65 + iloc];
            u64 b = __ballot(val > 0);
            if (ln == q) myw = b;
        }
        if (ln < 16) dst[(size_t)(i0 + wv * 16 + ln) * TW + jt] = myw;
        return;
    }
    bx -= PACK_BLOCKS;
    if (bx < NPROJ_BLOCKS) {
        float* row = smem;   // [4][FN]
        const int i = bx * 4 + wv;
        float2 r2 = *(const float2*)(nf + (size_t)i * FN + ln * 2);
        row[wv * FN + ln * 2] = r2.x; row[wv * FN + ln * 2 + 1] = r2.y;
        __syncthreads();
        float h0 = 0.f, h1 = 0.f;
#pragma unroll 8
        for (int k = 0; k < FN; ++k) {
            float nv = row[wv * FN + k];
            float2 w2 = *(const float2*)(Wn + (size_t)k * FN + ln * 2);
            h0 = fmaf(nv, w2.x, h0); h1 = fmaf(nv, w2.y, h1);
        }
        float2 as = *(const float2*)(pvn + ln * 2);
        float2 an = *(const float2*)(pvn + FN + ln * 2);
        float2 bs = *(const float2*)(pve + ln * 2);
        float pa = h0 * as.x + h1 * as.y;
        float pb = h0 * an.x + h1 * an.y;
        float pg = h0 * bs.x + h1 * bs.y;
#pragma unroll
        for (int off = 32; off > 0; off >>= 1) {
            pa += __shfl_down(pa, off, 64);
            pb += __shfl_down(pb, off, 64);
            pg += __shfl_down(pg, off, 64);
        }
        if (ln == 0) { alpha[i] = pa; beta[i] = pb; gamma[i] = pg; }
        return;
    }
    bx -= NPROJ_BLOCKS;
    if (bx < EPROJ_BLOCKS) {
        float* row = smem;   // [4][FE]
        const int e = bx * 4 + wv;
        row[wv * FE + ln] = ef[(size_t)e * FE + ln];
        __syncthreads();
        float h = 0.f;
#pragma unroll 8
        for (int k = 0; k < FE; ++k)
            h = fmaf(row[wv * FE + k], We[(size_t)k * FE + ln], h);
        float p = h * pve[FN + ln];
#pragma unroll
        for (int off = 32; off > 0; off >>= 1) p += __shfl_down(p, off, 64);
        if (ln == 0) betaE[e] = p;
        return;
    }
    bx -= EPROJ_BLOCKS;
    if (bx < PREPN_BLOCKS) {
        prep_b(nf, XbN, bx * 64, FN, 7, smem);
        return;
    }
    bx -= PREPN_BLOCKS;
    prep_b(ef, XbE, bx * 64, FE, 6, smem);
}

// ---- kernel 2: global maxes ----
__global__ __launch_bounds__(1024) void k_maxes(
    const float* __restrict__ beta, const float* __restrict__ betaE,
    float* __restrict__ maxes) {
    const float* src = blockIdx.x == 0 ? beta : betaE;
    const int n = blockIdx.x == 0 ? N_NODES : N_EDGES;
    float m = -3.0e38f;
#pragma unroll
    for (int t = threadIdx.x * 4; t < n; t += 4096) {
        float4 v = *(const float4*)(src + t);
        m = fmaxf(m, fmaxf(fmaxf(v.x, v.y), fmaxf(v.z, v.w)));
    }
#pragma unroll
    for (int off = 32; off > 0; off >>= 1) m = fmaxf(m, __shfl_down(m, off, 64));
    __shared__ float sm[16];
    if ((threadIdx.x & 63) == 0) sm[threadIdx.x >> 6] = m;
    __syncthreads();
    if (threadIdx.x == 0) {
        float mm = sm[0];
#pragma unroll
        for (int w = 1; w < 16; ++w) mm = fmaxf(mm, sm[w]);
        maxes[blockIdx.x] = mm;
    }
}

// ---- kernel 3: fused attention (node blocks then edge blocks), maskT, no shfl, no LDS ----
__global__ __launch_bounds__(256) void k_att(
    const unsigned short* __restrict__ XbN, const unsigned short* __restrict__ XbE,
    const unsigned* __restrict__ mTN, const unsigned* __restrict__ mTE,  // u32 view
    const float* __restrict__ alpha, const float* __restrict__ beta,
    const float* __restrict__ gamma, const float* __restrict__ betaE,
    const float* __restrict__ maxes,
    float* __restrict__ accN, float* __restrict__ zN, float* __restrict__ degN,
    float* __restrict__ accE, float* __restrict__ zE, float* __restrict__ degE) {
    const int t = threadIdx.x, l = t & 63, wid = t >> 6;
    const int l15 = l & 15, lq = l >> 4;
    int b = blockIdx.x;
    if (b < ATTN_BLOCKS) {
        // ---------------- node side ----------------
        const int bx = b & 31, bj = b >> 5;
        const int j0 = bj * (N_NODES / NJS);        // 256
        const int i0 = bx * 128 + wid * 32;
        const float a0 = alpha[i0 + l15], a1 = alpha[i0 + 16 + l15];
        const float mx = maxes[0];
        const float m0 = lrelu(a0 + mx), m1 = lrelu(a1 + mx);
        const unsigned* mr0 = mTN + (size_t)(i0 + l15) * (TWN * 2) + (j0 >> 5);
        const unsigned* mr1 = mr0 + (size_t)16 * (TWN * 2);
        f32x4 acc0[8] = {}, acc1[8] = {};
        float z0 = 0.f, z1 = 0.f;
        int d0 = 0, d1 = 0;
        const unsigned short* xb0 = XbN + (((size_t)(j0 >> 3) + lq) * FN + l15) * 8;
        const float* bb0 = beta + j0 + lq * 8;
        for (int ks = 0; ks < (N_NODES / NJS) / 32; ++ks) {   // 8
            const int jb = ks * 32;
            unsigned m32a = mr0[ks];
            unsigned m32b = mr1[ks];
            float4 b0v = *(const float4*)(bb0 + jb);
            float4 b1v = *(const float4*)(bb0 + jb + 4);
            float bv[8] = {b0v.x, b0v.y, b0v.z, b0v.w, b1v.x, b1v.y, b1v.z, b1v.w};
            bf16x8 wf0, wf1;
#pragma unroll
            for (int e = 0; e < 8; ++e) {
                int sh = lq * 8 + e;
                int mka = (int)((m32a >> sh) & 1u);
                int mkb = (int)((m32b >> sh) & 1u);
                float s0 = lrelu(a0 + bv[e]);
                float w0 = mka ? __expf(s0 - m0) : 0.f;
                float s1 = lrelu(a1 + bv[e]);
                float w1 = mkb ? __expf(s1 - m1) : 0.f;
                z0 += w0; z1 += w1; d0 += mka; d1 += mkb;
                wf0[e] = (short)f2bf(w0);
                wf1[e] = (short)f2bf(w1);
            }
            const unsigned short* xa = xb0 + (size_t)(jb >> 3) * (FN * 8);
#pragma unroll
            for (int mi = 0; mi < 8; ++mi) {
                bf16x8 a = *(const bf16x8*)(xa + mi * 128);
                acc0[mi] = __builtin_amdgcn_mfma_f32_16x16x32_bf16(a, wf0, acc0[mi], 0, 0, 0);
                acc1[mi] = __builtin_amdgcn_mfma_f32_16x16x32_bf16(a, wf1, acc1[mi], 0, 0, 0);
            }
        }
        float d0f = (float)d0, d1f = (float)d1;
        z0 += __shfl_xor(z0, 16, 64); z0 += __shfl_xor(z0, 32, 64);
        d0f += __shfl_xor(d0f, 16, 64); d0f += __shfl_xor(d0f, 32, 64);
        z1 += __shfl_xor(z1, 16, 64); z1 += __shfl_xor(z1, 32, 64);
        d1f += __shfl_xor(d1f, 16, 64); d1f += __shfl_xor(d1f, 32, 64);
        if (l < 16) {
            zN[bj * N_NODES + i0 + l] = z0;   degN[bj * N_NODES + i0 + l] = d0f;
            zN[bj * N_NODES + i0 + 16 + l] = z1;   degN[bj * N_NODES + i0 + 16 + l] = d1f;
        }
#pragma unroll
        for (int mi = 0; mi < 8; ++mi) {
            *(f32x4*)(accN + ((size_t)bj * N_NODES + i0 + l15) * FN + mi * 16 + lq * 4) = acc0[mi];
            *(f32x4*)(accN + ((size_t)bj * N_NODES + i0 + 16 + l15) * FN + mi * 16 + lq * 4) = acc1[mi];
        }
    } else {
        // ---------------- edge side ----------------
        b -= ATTN_BLOCKS;
        const int bx = b & 31, bj = b >> 5;
        const int j0 = bj * (N_EDGES / EJS);        // 512
        const int i0 = bx * 128 + wid * 32;
        const float a0 = gamma[i0 + l15], a1 = gamma[i0 + 16 + l15];
        const float mx = maxes[1];
        const float m0 = lrelu(a0 + mx), m1 = lrelu(a1 + mx);
        const unsigned* mr0 = mTE + (size_t)(i0 + l15) * (TWE * 2) + (j0 >> 5);
        const unsigned* mr1 = mr0 + (size_t)16 * (TWE * 2);
        f32x4 acc0[4] = {}, acc1[4] = {};
        float z0 = 0.f, z1 = 0.f;
        int d0 = 0, d1 = 0;
        const unsigned short* xb0 = XbE + (((size_t)(j0 >> 3) + lq) * FE + l15) * 8;
        const float* bb0 = betaE + j0 + lq * 8;
        for (int ks = 0; ks < (N_EDGES / EJS) / 32; ++ks) {   // 16
            const int jb = ks * 32;
            unsigned m32a = mr0[ks];
            unsigned m32b = mr1[ks];
            float4 b0v = *(const float4*)(bb0 + jb);
            float4 b1v = *(const float4*)(bb0 + jb + 4);
            float bv[8] = {b0v.x, b0v.y, b0v.z, b0v.w, b1v.x, b1v.y, b1v.z, b1v.w};
            bf16x8 wf0, wf1;
#pragma unroll
            for (int e = 0; e < 8; ++e) {
                int sh = lq * 8 + e;
                int mka = (int)((m32a >> sh) & 1u);
                int mkb = (int)((m32b >> sh) & 1u);
                float s0 = lrelu(a0 + bv[e]);
                float w0 = mka ? __expf(s0 - m0) : 0.f;
                float s1 = lrelu(a1 + bv[e]);
                float w1 = mkb ? __expf(s1 - m1) : 0.f;
                z0 += w0; z1 += w1; d0 += mka; d1 += mkb;
                wf0[e] = (short)f2bf(w0);
                wf1[e] = (short)f2bf(w1);
            }
            const unsigned short* xa = xb0 + (size_t)(jb >> 3) * (FE * 8);
#pragma unroll
            for (int mi = 0; mi < 4; ++mi) {
                bf16x8 a = *(const bf16x8*)(xa + mi * 128);
                acc0[mi] = __builtin_amdgcn_mfma_f32_16x16x32_bf16(a, wf0, acc0[mi], 0, 0, 0);
                acc1[mi] = __builtin_amdgcn_mfma_f32_16x16x32_bf16(a, wf1, acc1[mi], 0, 0, 0);
            }
        }
        float d0f = (float)d0, d1f = (float)d1;
        z0 += __shfl_xor(z0, 16, 64); z0 += __shfl_xor(z0, 32, 64);
        d0f += __shfl_xor(d0f, 16, 64); d0f += __shfl_xor(d0f, 32, 64);
        z1 += __shfl_xor(z1, 16, 64); z1 += __shfl_xor(z1, 32, 64);
        d1f += __shfl_xor(d1f, 16, 64); d1f += __shfl_xor(d1f, 32, 64);
        if (l < 16) {
            zE[bj * N_NODES + i0 + l] = z0;   degE[bj * N_NODES + i0 + l] = d0f;
            zE[bj * N_NODES + i0 + 16 + l] = z1;   degE[bj * N_NODES + i0 + 16 + l] = d1f;
        }
#pragma unroll
        for (int mi = 0; mi < 4; ++mi) {
            *(f32x4*)(accE + ((size_t)bj * N_NODES + i0 + l15) * FE + mi * 16 + lq * 4) = acc0[mi];
            *(f32x4*)(accE + ((size_t)bj * N_NODES + i0 + 16 + l15) * FE + mi * 16 + lq * 4) = acc1[mi];
        }
    }
}

// ---- kernel 4: fused epilogues ----
__global__ __launch_bounds__(256) void k_out(
    const float* __restrict__ accN, const float* __restrict__ zN, const float* __restrict__ degN,
    const float* __restrict__ accE, const float* __restrict__ zE, const float* __restrict__ degE,
    const float* __restrict__ Wn, const float* __restrict__ We,
    float* __restrict__ out) {
    __shared__ float ml[4][FN];
    const int wv = threadIdx.x >> 6, ln = threadIdx.x & 63;
    int b = blockIdx.x;
    if (b < N_NODES / 4) {
        const int i = b * 4 + wv;
        float s0 = 0.f, s1 = 0.f;
#pragma unroll
        for (int js = 0; js < NJS; ++js) {
            float2 v = *(const float2*)(accN + ((size_t)js * N_NODES + i) * FN + ln * 2);
            s0 += v.x; s1 += v.y;
        }
        float z = 0.f, d = 0.f;
#pragma unroll
        for (int js = 0; js < NJS; ++js) { z += zN[js * N_NODES + i]; d += degN[js * N_NODES + i]; }
        float zd = z * d;
        float inv = zd > 0.f ? 1.f / zd : 0.f;
        ml[wv][ln * 2] = s0 * inv; ml[wv][ln * 2 + 1] = s1 * inv;
        __syncthreads();
        float o0 = 0.f, o1 = 0.f;
#pragma unroll 8
        for (int k = 0; k < FN; ++k) {
            float mvv = ml[wv][k];
            float2 w2 = *(const float2*)(Wn + (size_t)k * FN + ln * 2);
            o0 = fmaf(mvv, w2.x, o0); o1 = fmaf(mvv, w2.y, o1);
        }
        out[(size_t)i * 192 + ln * 2] = lrelu(o0);
        out[(size_t)i * 192 + ln * 2 + 1] = lrelu(o1);
    } else {
        b -= N_NODES / 4;
        const int i = b * 4 + wv;
        float s = 0.f;
#pragma unroll
        for (int js = 0; js < EJS; ++js)
            s += accE[((size_t)js * N_NODES + i) * FE + ln];
        float z = 0.f, d = 0.f;
#pragma unroll
        for (int js = 0; js < EJS; ++js) { z += zE[js * N_NODES + i]; d += degE[js * N_NODES + i]; }
        float zd = z * d;
        float inv = zd > 0.f ? 1.f / zd : 0.f;
        ml[wv][ln] = s * inv;
        __syncthreads();
        float o = 0.f;
#pragma unroll 8
        for (int k = 0; k < FE; ++k)
            o = fmaf(ml[wv][k], We[(size_t)k * FE + ln], o);
        out[(size_t)i * 192 + 128 + ln] = lrelu(o);
    }
}

extern "C" void kernel_launch(void* const* d_in, const int* in_sizes, int n_in,
                              void* d_out, int out_size, void* d_ws, size_t ws_size,
                              hipStream_t stream) {
    (void)in_sizes; (void)n_in; (void)out_size; (void)ws_size;
    const float* nf   = (const float*)d_in[0];
    const float* ef   = (const float*)d_in[1];
    const int*   adj  = (const int*)d_in[2];
    const int*   eadj = (const int*)d_in[3];
    const float* Wn   = (const float*)d_in[4];
    const float* We   = (const float*)d_in[5];
    const float* pvn  = (const float*)d_in[6];
    const float* pve  = (const float*)d_in[7];
    float* out = (float*)d_out;

    u64* maskTN = (u64*)d_ws;                               // 4096*64*8  = 2 MB
    u64* maskTE = maskTN + (size_t)N_NODES * TWN;           // 4096*256*8 = 8 MB
    float* alpha = (float*)(maskTE + (size_t)N_NODES * TWE);
    float* beta  = alpha + 4096;
    float* gamma = beta + 4096;
    float* betaE = gamma + 4096;
    float* maxes = betaE + 16384;                           // 64 (padded)
    unsigned short* XbN = (unsigned short*)(maxes + 64);            // 1 MB
    unsigned short* XbE = XbN + (size_t)(N_NODES / 8) * FN * 8;     // 2 MB
    float* accN = (float*)(XbE + (size_t)(N_EDGES / 8) * FE * 8);   // 33.5 MB
    float* zN   = accN + (size_t)NJS * N_NODES * FN;
    float* degN = zN + (size_t)NJS * N_NODES;
    float* accE = degN + (size_t)NJS * N_NODES;                     // 33.5 MB
    float* zE   = accE + (size_t)EJS * N_NODES * FE;
    float* degE = zE + (size_t)EJS * N_NODES;

    k_front<<<FRONT_BLOCKS, 256, 0, stream>>>(nf, ef, adj, eadj, Wn, We, pvn, pve,
                                              maskTN, maskTE, alpha, beta, gamma, betaE, XbN, XbE);
    k_maxes<<<2, 1024, 0, stream>>>(beta, betaE, maxes);
    k_att<<<ATTN_BLOCKS + ATTE_BLOCKS, 256, 0, stream>>>(
        XbN, XbE, (const unsigned*)maskTN, (const unsigned*)maskTE,
        alpha, beta, gamma, betaE, maxes, accN, zN, degN, accE, zE, degE);
    k_out<<<N_NODES / 4 + N_NODES / 4, 256, 0, stream>>>(
        accN, zN, degN, accE, zE, degE, Wn, We, out);
}